// Round 1
// baseline (19.116 us; speedup 1.0000x reference)
//
#include <hip/hip_runtime.h>
#include <hip/hip_bf16.h>

// out[l,m,p,o] = sum_{k,j,i} w[k,j,l,m,i] * s[2*(l+k-1)+j, p, (o+i-2) mod 56]
//   where s[c,p,q] = x[c,p,q] + x[c+64,p,q]
//   valid only when 0 <= l+k-1 < 32 and 0 <= o+i-1 < 56
// final[l*4+m, (p+1)%56, o] = out[l,m,p,o]
__global__ __launch_bounds__(256) void fused_unfold_einsum(
    const float* __restrict__ x,   // (128, 56, 56)
    const float* __restrict__ w,   // (3, 2, 32, 4, 3)
    float* __restrict__ out)       // (128, 56, 56)
{
    const int bid = blockIdx.x;
    const int l  = bid / 14;        // 0..31
    const int pg = bid % 14;        // 0..13
    const int tid = threadIdx.x;
    const int po = tid >> 6;        // 0..3
    const int o  = tid & 63;        // 0..63, active if < 56
    const int p  = pg * 4 + po;     // 0..55

    if (o >= 56) return;

    // q-source columns for i = 0,1,2 (all clamped in-bounds; validity separate)
    const int  qs0 = (o >= 2) ? (o - 2) : 55;   // used when o >= 1; o==1 -> 55
    const int  qs1 = (o >= 1) ? (o - 1) : 55;   // o==0 -> 55 (the roll)
    const int  qs2 = o;
    const bool qv0 = (o >= 1);
    const bool qv2 = (o <= 54);

    float acc0 = 0.f, acc1 = 0.f, acc2 = 0.f, acc3 = 0.f;

    const int rowoff = p * 56;

    #pragma unroll
    for (int k = 0; k < 3; ++k) {
        const int lsrc = l + k - 1;
        if (lsrc < 0 || lsrc >= 32) continue;
        #pragma unroll
        for (int j = 0; j < 2; ++j) {
            const int c = 2 * lsrc + j;
            const float* __restrict__ r0 = x + (c * 3136 + rowoff);
            const float* __restrict__ r1 = r0 + 64 * 3136;

            const float v0 = qv0 ? (r0[qs0] + r1[qs0]) : 0.0f;
            const float v1 =        r0[qs1] + r1[qs1];
            const float v2 = qv2 ? (r0[qs2] + r1[qs2]) : 0.0f;

            // w[k,j,l,m,i] at ((k*2+j)*32 + l)*12 + m*3 + i  (block-uniform base)
            const float* __restrict__ wp = w + ((k * 2 + j) * 32 + l) * 12;
            acc0 = fmaf(wp[0],  v0, fmaf(wp[1],  v1, fmaf(wp[2],  v2, acc0)));
            acc1 = fmaf(wp[3],  v0, fmaf(wp[4],  v1, fmaf(wp[5],  v2, acc1)));
            acc2 = fmaf(wp[6],  v0, fmaf(wp[7],  v1, fmaf(wp[8],  v2, acc2)));
            acc3 = fmaf(wp[9],  v0, fmaf(wp[10], v1, fmaf(wp[11], v2, acc3)));
        }
    }

    const int p_out = (p + 1 == 56) ? 0 : (p + 1);
    const int base = ((l * 4) * 56 + p_out) * 56 + o;  // channel stride 3136
    out[base]            = acc0;
    out[base + 3136]     = acc1;
    out[base + 2 * 3136] = acc2;
    out[base + 3 * 3136] = acc3;
}

extern "C" void kernel_launch(void* const* d_in, const int* in_sizes, int n_in,
                              void* d_out, int out_size, void* d_ws, size_t ws_size,
                              hipStream_t stream) {
    const float* x = (const float*)d_in[0];
    const float* w = (const float*)d_in[1];
    float* out = (float*)d_out;

    dim3 grid(32 * 14);   // l * p-groups
    dim3 block(256);      // 4 p-rows x 64 lanes (56 active)
    fused_unfold_einsum<<<grid, block, 0, stream>>>(x, w, out);
}

// Round 2
// 9.861 us; speedup vs baseline: 1.9385x; 1.9385x over previous
//
#include <hip/hip_runtime.h>
#include <hip/hip_bf16.h>

// out[l,m,p,o] = sum_{k,j,i} w[k,j,l,m,i] * s[2*(l+k-1)+j, p, (o+i-2) mod 56]
//   s[c,p,q] = x[c,p,q] + x[c+64,p,q]
//   contribution valid iff 0 <= l+k-1 < 32 and 0 <= o+i-1 < 56
// final[l*4+m, (p+1)%56, o] = out[l,m,p,o]
//
// Block: 256 threads = 4 p-rows x 64 lanes; grid (pg=14, l*4+m=128).
// l,m block-uniform -> weight reads are scalar; s staged in LDS via float4.
__global__ __launch_bounds__(256) void fused_unfold_einsum(
    const float* __restrict__ x,   // (128, 56, 56)
    const float* __restrict__ w,   // (3, 2, 32, 4, 3)
    float* __restrict__ out)       // (128, 56, 56)
{
    __shared__ float sblk[6][4][56];   // [kk*2+j][po][q]

    const int pg = blockIdx.x;         // 0..13
    const int lm = blockIdx.y;         // 0..127
    const int l  = lm >> 2;            // 0..31 (uniform)
    const int m  = lm & 3;             // 0..3  (uniform)
    const int tid = threadIdx.x;

    // ---- stage s into LDS: 6 channels x 4 rows x 56 cols = 336 float4 slots ----
    #pragma unroll
    for (int it = 0; it < 2; ++it) {
        const int s = tid + it * 256;
        if (s < 336) {
            const int ch  = s / 56;            // 0..5
            const int rem = s - ch * 56;
            const int po  = rem / 14;          // 0..3
            const int q4  = rem - po * 14;     // 0..13
            const int kk  = ch >> 1;
            const int lsrc = l - 1 + kk;
            float4 val;
            if (lsrc >= 0 && lsrc < 32) {
                const int c = 2 * lsrc + (ch & 1);
                const float* base = x + c * 3136 + (pg * 4 + po) * 56 + q4 * 4;
                const float4 a = *(const float4*)base;
                const float4 b = *(const float4*)(base + 64 * 3136);
                val = make_float4(a.x + b.x, a.y + b.y, a.z + b.z, a.w + b.w);
            } else {
                val = make_float4(0.f, 0.f, 0.f, 0.f);
            }
            *(float4*)&sblk[ch][po][q4 * 4] = val;
        }
    }
    __syncthreads();

    // ---- compute: each thread -> one output (l,m,p,o) ----
    const int po = tid >> 6;           // wave-uniform
    const int o  = tid & 63;
    if (o >= 56) return;

    const int q0 = (o >= 2) ? (o - 2) : (o + 54);  // i=0 source (mod-56 roll)
    const int q1 = (o >= 1) ? (o - 1) : 55;        // i=1 source
    const int q2 = o;                              // i=2 source
    const bool v0ok = (o >= 1);
    const bool v2ok = (o <= 54);

    float acc = 0.f;
    #pragma unroll
    for (int kk = 0; kk < 3; ++kk) {
        #pragma unroll
        for (int j = 0; j < 2; ++j) {
            const float* row = sblk[kk * 2 + j][po];
            const float v0 = v0ok ? row[q0] : 0.f;
            const float v1 = row[q1];
            const float v2 = v2ok ? row[q2] : 0.f;
            const float* wp = w + (((kk * 2 + j) * 32 + l) * 4 + m) * 3;  // scalar
            acc = fmaf(wp[0], v0, fmaf(wp[1], v1, fmaf(wp[2], v2, acc)));
        }
    }

    const int p = pg * 4 + po;
    const int p_out = (p + 1 == 56) ? 0 : (p + 1);
    out[((l * 4 + m) * 56 + p_out) * 56 + o] = acc;
}

extern "C" void kernel_launch(void* const* d_in, const int* in_sizes, int n_in,
                              void* d_out, int out_size, void* d_ws, size_t ws_size,
                              hipStream_t stream) {
    const float* x = (const float*)d_in[0];
    const float* w = (const float*)d_in[1];
    float* out = (float*)d_out;

    dim3 grid(14, 128);   // (p-groups, l*4+m)
    dim3 block(256);      // 4 p-rows x 64 lanes (56 active)
    fused_unfold_einsum<<<grid, block, 0, stream>>>(x, w, out);
}